// Round 6
// baseline (119.766 us; speedup 1.0000x reference)
//
#include <hip/hip_runtime.h>

typedef _Float16 f16;
typedef f16 f16x8 __attribute__((ext_vector_type(8)));
typedef f16 f16x4 __attribute__((ext_vector_type(4)));
typedef f16 f16x2 __attribute__((ext_vector_type(2)));
typedef float f32x4 __attribute__((ext_vector_type(4)));

union F8 { uint4 u4; f16x8 v; f16x2 h[4]; f16 e[8]; };

// ---------------------------------------------------------------------------
// Prep (weights only):
//   W1P[u][w][v]  = f16(W1s[u][v][w])   (128 x 128 x 32)
//   W2P[u][w2][v] = f16(W2[u][v][w2])   (128 x 32 x 32)
// ---------------------------------------------------------------------------
__global__ __launch_bounds__(256) void prep_kernel(
    const float* __restrict__ W1s, const float* __restrict__ W2,
    f16* __restrict__ W1P, f16* __restrict__ W2P)
{
    __shared__ f16 T[32 * 36];
    const int b = blockIdx.x, t = threadIdx.x;

    const float* src; f16* dst; int u, w0, W;
    if (b < 512) { u = b >> 2; w0 = (b & 3) * 32; W = 128; src = W1s; dst = W1P; }
    else         { u = b - 512; w0 = 0;           W = 32;  src = W2;  dst = W2P; }
    {
        int v = t >> 3, wq = t & 7;
        float4 f = *(const float4*)(src + (size_t)(u * 32 + v) * W + w0 + wq * 4);
        T[v * 36 + wq * 4 + 0] = (f16)f.x;
        T[v * 36 + wq * 4 + 1] = (f16)f.y;
        T[v * 36 + wq * 4 + 2] = (f16)f.z;
        T[v * 36 + wq * 4 + 3] = (f16)f.w;
    }
    __syncthreads();
    {
        int w = t >> 3, vr = t & 7;
        f16x4 o = { T[(vr * 4 + 0) * 36 + w], T[(vr * 4 + 1) * 36 + w],
                    T[(vr * 4 + 2) * 36 + w], T[(vr * 4 + 3) * 36 + w] };
        *(f16x4*)(dst + (size_t)u * (W * 32) + (size_t)(w0 + w) * 32 + vr * 4) = o;
    }
}

// ---------------------------------------------------------------------------
// K1: GEMM1 + silu.  Block = 64 rows x 64 cols, 256 thr.
// Wave wv: mtp = wv&1 (rows 32*mtp..+32, 2 m-tiles), cs = wv>>1 (32-col
// strip = 2 col-tiles).  Per u: 8 pk_mul + 4 MFMA (a-frag amortized over
// 2 col-tiles -> MFMA-bound).  Grid (128,2): B L2 traffic = 128 MB.
// Depth-8 B ring, all register arrays constant-indexed (full unroll).
// ---------------------------------------------------------------------------
__global__ __launch_bounds__(256, 2) void gemm1_kernel(
    const float* __restrict__ node_vec, const float* __restrict__ attr,
    const f16* __restrict__ W1P, const float* __restrict__ b1s,
    f16* __restrict__ s_act)
{
    __shared__ alignas(16) f16 s_lds[64 * 136];

    const int t  = threadIdx.x;
    const int n0 = blockIdx.x * 64;
    const int wv = t >> 6, l = t & 63, lr = l & 15, q = l >> 4;
    const int mtp = wv & 1, cs = wv >> 1;
    const int c0 = blockIdx.y * 64 + cs * 32;        // wave's 32-col strip
    const int r0 = 32 * mtp;                          // wave's row base (local)

    // stage s tile: 64 rows x 128 cols, f32 -> f16 (8 float4 per thread)
    #pragma unroll
    for (int i = 0; i < 8; ++i) {
        int idx = t + 256 * i;
        int r = idx >> 5, c4 = idx & 31;
        float4 f = *(const float4*)(node_vec + (size_t)(n0 + r) * 480 + c4 * 4);
        f16x4 o = { (f16)f.x, (f16)f.y, (f16)f.z, (f16)f.w };
        *(f16x4*)(s_lds + r * 136 + c4 * 4) = o;
    }

    // attr fragments (K-invariant) for the wave's 2 m-tiles
    F8 af0, af1;
    #pragma unroll
    for (int kk = 0; kk < 4; ++kk) {
        float2 fa = *(const float2*)(attr + (size_t)(n0 + r0 + lr) * 32 + q * 8 + kk * 2);
        float2 fb = *(const float2*)(attr + (size_t)(n0 + r0 + 16 + lr) * 32 + q * 8 + kk * 2);
        af0.h[kk] = f16x2{ (f16)fa.x, (f16)fa.y };
        af1.h[kk] = f16x2{ (f16)fb.x, (f16)fb.y };
    }

    // prime B ring (depth 8 u-slots x 2 col-tiles); frag(u,ct)=W1P[u][c0+16ct+lr][q*8..+7]
    const f16* Bp = W1P + ((size_t)(c0 + lr)) * 32 + q * 8;   // +512 for ct=1; +4096/u
    f16x8 B0[8], B1[8];
    #pragma unroll
    for (int j = 0; j < 8; ++j) {
        B0[j] = *(const f16x8*)(Bp + (size_t)j * 4096);
        B1[j] = *(const f16x8*)(Bp + (size_t)j * 4096 + 512);
    }

    __syncthreads();

    f32x4 acc00 = {0,0,0,0}, acc01 = {0,0,0,0};   // [mt][ct]
    f32x4 acc10 = {0,0,0,0}, acc11 = {0,0,0,0};

    F8 s8[2][2];   // [buf][mt] — constant indices only (full unroll)
    s8[0][0].v = *(const f16x8*)(s_lds + (r0 + lr) * 136);
    s8[0][1].v = *(const f16x8*)(s_lds + (r0 + 16 + lr) * 136);

    #pragma unroll
    for (int uo = 0; uo < 16; ++uo) {
        const int cur = uo & 1, nxt = cur ^ 1;
        const int uon = (uo + 1 < 16) ? uo + 1 : 15;
        s8[nxt][0].v = *(const f16x8*)(s_lds + (r0 + lr) * 136 + uon * 8);
        s8[nxt][1].v = *(const f16x8*)(s_lds + (r0 + 16 + lr) * 136 + uon * 8);
        #pragma unroll
        for (int j = 0; j < 8; ++j) {
            const int u = uo * 8 + j;
            f16x8 bf0 = B0[j], bf1 = B1[j];
            const int un = (u + 8 < 128) ? (u + 8) : u;   // constant
            B0[j] = *(const f16x8*)(Bp + (size_t)un * 4096);
            B1[j] = *(const f16x8*)(Bp + (size_t)un * 4096 + 512);
            f16 sv0 = s8[cur][0].e[j];
            f16 sv1 = s8[cur][1].e[j];
            f16x2 sb0 = { sv0, sv0 }, sb1 = { sv1, sv1 };
            F8 a0, a1;
            #pragma unroll
            for (int kk = 0; kk < 4; ++kk) {
                a0.h[kk] = sb0 * af0.h[kk];
                a1.h[kk] = sb1 * af1.h[kk];
            }
            acc00 = __builtin_amdgcn_mfma_f32_16x16x32_f16(a0.v, bf0, acc00, 0, 0, 0);
            acc01 = __builtin_amdgcn_mfma_f32_16x16x32_f16(a0.v, bf1, acc01, 0, 0, 0);
            acc10 = __builtin_amdgcn_mfma_f32_16x16x32_f16(a1.v, bf0, acc10, 0, 0, 0);
            acc11 = __builtin_amdgcn_mfma_f32_16x16x32_f16(a1.v, bf1, acc11, 0, 0, 0);
        }
    }

    // epilogue: scale, bias, silu -> s_act.  C layout: col=lr, row=q*4+reg
    const float bv0 = b1s[c0 + lr];
    const float bv1 = b1s[c0 + 16 + lr];
    #pragma unroll
    for (int reg = 0; reg < 4; ++reg) {
        int ra = n0 + r0 + q * 4 + reg;
        int rb = n0 + r0 + 16 + q * 4 + reg;
        float v00 = acc00[reg] * 0.015625f + bv0;
        float v01 = acc01[reg] * 0.015625f + bv1;
        float v10 = acc10[reg] * 0.015625f + bv0;
        float v11 = acc11[reg] * 0.015625f + bv1;
        s_act[(size_t)ra * 128 + c0 + lr]      = (f16)(v00 / (1.f + __expf(-v00)));
        s_act[(size_t)ra * 128 + c0 + 16 + lr] = (f16)(v01 / (1.f + __expf(-v01)));
        s_act[(size_t)rb * 128 + c0 + lr]      = (f16)(v10 / (1.f + __expf(-v10)));
        s_act[(size_t)rb * 128 + c0 + 16 + lr] = (f16)(v11 / (1.f + __expf(-v11)));
    }
}

// ---------------------------------------------------------------------------
// K2: GEMM2 + head.  Block = 32 rows x all 32 cols, 256 thr.  Grid 256.
// 4 waves split u2 (32 each); depth-8 B ring x 2 col-tiles; LDS reduction;
// fused 32x32 head.  All register arrays constant-indexed.
// ---------------------------------------------------------------------------
__global__ __launch_bounds__(256, 2) void gemm2_head_kernel(
    const f16* __restrict__ s_act, const float* __restrict__ attr,
    const f16* __restrict__ W2P, const float* __restrict__ b2,
    const float* __restrict__ W3, const float* __restrict__ b3,
    const float* __restrict__ W4, const float* __restrict__ b4,
    float* __restrict__ out)
{
    __shared__ alignas(16) f16 s_lds[32 * 136];
    __shared__ alignas(16) float red[4][32 * 36];
    __shared__ alignas(16) float W3_lds[32 * 36];
    __shared__ alignas(16) float h_lds[32 * 36];

    const int t  = threadIdx.x;
    const int n0 = blockIdx.x * 32;
    const int wv = t >> 6, l = t & 63, lr = l & 15, q = l >> 4;
    const int u0 = wv * 32;

    const f16* B2p = W2P + ((size_t)u0 * 32 + lr) * 32 + q * 8;
    f16x8 B0[8], B1[8];
    #pragma unroll
    for (int j = 0; j < 8; ++j) {
        B0[j] = *(const f16x8*)(B2p + (size_t)j * 1024);
        B1[j] = *(const f16x8*)(B2p + (size_t)j * 1024 + 512);
    }

    F8 af0, af1;
    #pragma unroll
    for (int kk = 0; kk < 4; ++kk) {
        float2 fa = *(const float2*)(attr + (size_t)(n0 + lr) * 32 + q * 8 + kk * 2);
        float2 fb = *(const float2*)(attr + (size_t)(n0 + 16 + lr) * 32 + q * 8 + kk * 2);
        af0.h[kk] = f16x2{ (f16)fa.x, (f16)fa.y };
        af1.h[kk] = f16x2{ (f16)fb.x, (f16)fb.y };
    }

    #pragma unroll
    for (int i = 0; i < 2; ++i) {
        int ch = t + 256 * i;
        int r = ch >> 4, c8 = ch & 15;
        *(uint4*)(s_lds + r * 136 + c8 * 8) =
            *(const uint4*)(s_act + (size_t)(n0 + r) * 128 + c8 * 8);
    }
    { int i = t >> 3, jj = (t & 7) * 4;
      *(f32x4*)(W3_lds + i * 36 + jj) = *(const f32x4*)(W3 + i * 32 + jj); }
    __syncthreads();

    f32x4 acc00 = {0,0,0,0}, acc01 = {0,0,0,0};
    f32x4 acc10 = {0,0,0,0}, acc11 = {0,0,0,0};

    F8 s8[2][2];
    s8[0][0].v = *(const f16x8*)(s_lds + lr * 136 + u0);
    s8[0][1].v = *(const f16x8*)(s_lds + (16 + lr) * 136 + u0);

    #pragma unroll
    for (int uo = 0; uo < 4; ++uo) {
        const int cur = uo & 1, nxt = cur ^ 1;
        const int uon = (uo + 1 < 4) ? uo + 1 : 3;
        s8[nxt][0].v = *(const f16x8*)(s_lds + lr * 136 + u0 + uon * 8);
        s8[nxt][1].v = *(const f16x8*)(s_lds + (16 + lr) * 136 + u0 + uon * 8);
        #pragma unroll
        for (int j = 0; j < 8; ++j) {
            const int k = uo * 8 + j;
            f16x8 bf0 = B0[j], bf1 = B1[j];
            const int kn = (k + 8 < 32) ? (k + 8) : k;
            B0[j] = *(const f16x8*)(B2p + (size_t)kn * 1024);
            B1[j] = *(const f16x8*)(B2p + (size_t)kn * 1024 + 512);
            f16 sv0 = s8[cur][0].e[j];
            f16 sv1 = s8[cur][1].e[j];
            f16x2 sb0 = { sv0, sv0 }, sb1 = { sv1, sv1 };
            F8 a0, a1;
            #pragma unroll
            for (int kk = 0; kk < 4; ++kk) {
                a0.h[kk] = sb0 * af0.h[kk];
                a1.h[kk] = sb1 * af1.h[kk];
            }
            acc00 = __builtin_amdgcn_mfma_f32_16x16x32_f16(a0.v, bf0, acc00, 0, 0, 0);
            acc01 = __builtin_amdgcn_mfma_f32_16x16x32_f16(a0.v, bf1, acc01, 0, 0, 0);
            acc10 = __builtin_amdgcn_mfma_f32_16x16x32_f16(a1.v, bf0, acc10, 0, 0, 0);
            acc11 = __builtin_amdgcn_mfma_f32_16x16x32_f16(a1.v, bf1, acc11, 0, 0, 0);
        }
    }

    #pragma unroll
    for (int reg = 0; reg < 4; ++reg) {
        red[wv][(q * 4 + reg) * 36 + lr]           = acc00[reg];
        red[wv][(q * 4 + reg) * 36 + 16 + lr]      = acc01[reg];
        red[wv][(16 + q * 4 + reg) * 36 + lr]      = acc10[reg];
        red[wv][(16 + q * 4 + reg) * 36 + 16 + lr] = acc11[reg];
    }
    __syncthreads();

    {
        int row = t >> 3, c4 = (t & 7) * 4;
        f32x4 s = *(const f32x4*)(&red[0][row * 36 + c4]);
        s = s + *(const f32x4*)(&red[1][row * 36 + c4]);
        s = s + *(const f32x4*)(&red[2][row * 36 + c4]);
        s = s + *(const f32x4*)(&red[3][row * 36 + c4]);
        #pragma unroll
        for (int e = 0; e < 4; ++e)
            h_lds[row * 36 + c4 + e] = s[e] * 0.015625f + b2[c4 + e];
    }
    __syncthreads();

    {
        int node = t >> 3, j4 = (t & 7) * 4;
        float a0 = 0.f, a1 = 0.f, a2 = 0.f, a3 = 0.f;
        #pragma unroll
        for (int i = 0; i < 32; ++i) {
            float hv = h_lds[node * 36 + i];
            a0 += hv * W3_lds[i * 36 + j4 + 0];
            a1 += hv * W3_lds[i * 36 + j4 + 1];
            a2 += hv * W3_lds[i * 36 + j4 + 2];
            a3 += hv * W3_lds[i * 36 + j4 + 3];
        }
        const float inv = 0.17677669529663687f;  // 1/sqrt(32)
        float p = 0.f;
        float aa[4] = { a0, a1, a2, a3 };
        #pragma unroll
        for (int e = 0; e < 4; ++e) {
            float tv = aa[e] * inv + b3[j4 + e];
            float g  = tv / (1.f + __expf(-tv));
            p += g * W4[j4 + e] * inv;
        }
        p += __shfl_xor(p, 1);
        p += __shfl_xor(p, 2);
        p += __shfl_xor(p, 4);
        if ((t & 7) == 0) out[n0 + node] = p + b4[0];
    }
}

// ---------------------------------------------------------------------------
extern "C" void kernel_launch(void* const* d_in, const int* in_sizes, int n_in,
                              void* d_out, int out_size, void* d_ws, size_t ws_size,
                              hipStream_t stream)
{
    const float* node_vec = (const float*)d_in[0];
    const float* attr     = (const float*)d_in[1];
    const float* W1s      = (const float*)d_in[2];
    const float* b1s      = (const float*)d_in[3];
    // d_in[4..7] (W1g,b1g,W1v1,W1v2) are dead code w.r.t. pred_energy
    const float* W2       = (const float*)d_in[8];
    const float* b2       = (const float*)d_in[9];
    const float* W3       = (const float*)d_in[10];
    const float* b3       = (const float*)d_in[11];
    const float* W4       = (const float*)d_in[12];
    const float* b4       = (const float*)d_in[13];
    float* out = (float*)d_out;

    char* ws = (char*)d_ws;
    f16* W1P   = (f16*)(ws);                  // 128*128*32*2 = 1 MiB
    f16* W2P   = (f16*)(ws + (1u << 20));     // 128*32*32*2  = 256 KiB
    f16* s_act = (f16*)(ws + (1280u << 10));  // 8192*128*2   = 2 MiB

    prep_kernel<<<640, 256, 0, stream>>>(W1s, W2, W1P, W2P);
    gemm1_kernel<<<dim3(128, 2), 256, 0, stream>>>(node_vec, attr, W1P, b1s, s_act);
    gemm2_head_kernel<<<256, 256, 0, stream>>>(s_act, attr, W2P, b2,
                                               W3, b3, W4, b4, out);
}